// Round 1
// baseline (368.279 us; speedup 1.0000x reference)
//
#include <hip/hip_runtime.h>
#include <hip/hip_bf16.h>

// SimpleMultiheadAttention on gfx950.
// d_in: 0 query1,1 query2,2 key,3 value, then (Wq,bq),(Wq2,bq2),(Wq3,bq3),(Wk,bk),(Wv,bv),(Wo,bo)
// d_out: output [2,1024,1024] fp32 then a1 [2,16,1024,1024] fp32.
// Plan: bf16 MFMA everywhere; global softmax via sum-pass + recompute-pass.

#define B_ 2
#define T_ 1024
#define E_ 1024
#define H_ 16
#define HD_ 64
#define BH_ 32

typedef float f32x4 __attribute__((ext_vector_type(4)));
typedef short bfrag __attribute__((ext_vector_type(8)));   // 8 x bf16

__device__ __forceinline__ unsigned short f2b(float f) {
  unsigned int u = __float_as_uint(f);
  u += 0x7fffu + ((u >> 16) & 1u);          // RNE (inputs finite)
  return (unsigned short)(u >> 16);
}

// ---------------------------------------------------------------- convert
struct CvtArgs { const float* src[10]; unsigned short* dst[10]; int n[10]; };

__global__ __launch_bounds__(256) void cvt_kernel(CvtArgs a) {
  const int z = blockIdx.y;
  const float* __restrict__ s = a.src[z];
  unsigned short* __restrict__ d = a.dst[z];
  const int n = a.n[z];
  const int stride = gridDim.x * 256 * 4;
  for (int i = (blockIdx.x * 256 + threadIdx.x) * 4; i < n; i += stride) {
    float4 v = *(const float4*)(s + i);
    ushort4 o;
    o.x = f2b(v.x); o.y = f2b(v.y); o.z = f2b(v.z); o.w = f2b(v.w);
    *(ushort4*)(d + i) = o;
  }
}

// ---------------------------------------------------------------- GEMM core
// C[128x128] tile of A[2048x1024] * W[1024x1024]^T (both row-major [row][k] bf16).
// 256 threads = 4 waves in 2x2; per wave 4x4 tiles of 16x16 (MFMA 16x16x32).
__device__ __forceinline__ void mm128_core(const unsigned short* __restrict__ A,
                                           const unsigned short* __restrict__ W,
                                           int m0, int n0,
                                           unsigned short* As, unsigned short* Bs,
                                           f32x4 acc[4][4]) {
  const int tid  = threadIdx.x;
  const int lane = tid & 63, w = tid >> 6;
  const int lrow = lane & 15, quad = lane >> 4;
  const int wm = (w >> 1) * 64, wn = (w & 1) * 64;
  const int srow = tid >> 2, soff = (tid & 3) * 8;   // staging: 8 bf16 per load

  const unsigned short* Ar0 = A + (size_t)(m0 + srow) * E_ + soff;
  const unsigned short* Ar1 = Ar0 + (size_t)64 * E_;
  const unsigned short* Br0 = W + (size_t)(n0 + srow) * E_ + soff;
  const unsigned short* Br1 = Br0 + (size_t)64 * E_;

  for (int k0 = 0; k0 < E_; k0 += 32) {
    int4 a0 = *(const int4*)(Ar0 + k0);
    int4 a1 = *(const int4*)(Ar1 + k0);
    int4 b0 = *(const int4*)(Br0 + k0);
    int4 b1 = *(const int4*)(Br1 + k0);
    __syncthreads();                       // prev-iter LDS reads done
    *(int4*)(As + srow * 32 + soff)        = a0;
    *(int4*)(As + (srow + 64) * 32 + soff) = a1;
    *(int4*)(Bs + srow * 32 + soff)        = b0;
    *(int4*)(Bs + (srow + 64) * 32 + soff) = b1;
    __syncthreads();
    bfrag af[4], bf_[4];
#pragma unroll
    for (int mt = 0; mt < 4; mt++)
      af[mt] = *(const bfrag*)(As + (wm + mt * 16 + lrow) * 32 + quad * 8);
#pragma unroll
    for (int nt = 0; nt < 4; nt++)
      bf_[nt] = *(const bfrag*)(Bs + (wn + nt * 16 + lrow) * 32 + quad * 8);
#pragma unroll
    for (int mt = 0; mt < 4; mt++)
#pragma unroll
      for (int nt = 0; nt < 4; nt++)
        acc[mt][nt] = __builtin_amdgcn_mfma_f32_16x16x32_bf16(af[mt], bf_[nt], acc[mt][nt], 0, 0, 0);
  }
}

// ---------------------------------------------------------------- projections
struct ProjArgs {
  const unsigned short* X[5];
  const unsigned short* W[5];
  const float* bias[5];
  unsigned short* dst[5];
};

__global__ __launch_bounds__(256) void proj_kernel(ProjArgs pa) {
  __shared__ unsigned short As[128 * 32];
  __shared__ unsigned short Bs[128 * 32];
  const int z = blockIdx.z;
  const int m0 = blockIdx.y * 128, n0 = blockIdx.x * 128;
  f32x4 acc[4][4];
#pragma unroll
  for (int mt = 0; mt < 4; mt++)
#pragma unroll
    for (int nt = 0; nt < 4; nt++) acc[mt][nt] = (f32x4)0.f;

  mm128_core(pa.X[z], pa.W[z], m0, n0, As, Bs, acc);

  const int tid = threadIdx.x, lane = tid & 63, w = tid >> 6;
  const int lrow = lane & 15, quad = lane >> 4;
  const int wm = (w >> 1) * 64, wn = (w & 1) * 64;
  const float* __restrict__ bias = pa.bias[z];
  unsigned short* __restrict__ dst = pa.dst[z];
  float bv[4];
#pragma unroll
  for (int nt = 0; nt < 4; nt++) bv[nt] = bias[n0 + wn + nt * 16 + lrow];
#pragma unroll
  for (int mt = 0; mt < 4; mt++)
#pragma unroll
    for (int nt = 0; nt < 4; nt++)
#pragma unroll
      for (int ii = 0; ii < 4; ii++) {
        const int m = m0 + wm + mt * 16 + quad * 4 + ii;    // (b,t)
        const int n = n0 + wn + nt * 16 + lrow;             // (h,d)
        const float v = acc[mt][nt][ii] + bv[nt];
        const int b = m >> 10, t = m & 1023, h = n >> 6, dd = n & 63;
        size_t idx;
        if (z == 4)  // V transposed: [bh][d][t]
          idx = ((size_t)((b * H_ + h) * HD_ + dd)) * T_ + t;
        else         // Q/K: [bh][t][d]
          idx = ((size_t)((b * H_ + h) * T_ + t)) * HD_ + dd;
        dst[idx] = f2b(v);
      }
}

// ---------------------------------------------------------------- sum pass
// block: (t-tile 128, bh). 4 waves = (tw,sw) quadrants. Direct global frag loads.
__global__ __launch_bounds__(256) void attn_sums_kernel(
    const unsigned short* __restrict__ Q1, const unsigned short* __restrict__ Q2,
    const unsigned short* __restrict__ Q3, const unsigned short* __restrict__ Kh,
    float* __restrict__ sums) {
  const int tid = threadIdx.x, lane = tid & 63, w = tid >> 6;
  const int lrow = lane & 15, quad = lane >> 4;
  const int tw = w >> 1, sw = w & 1;
  const int bh = blockIdx.y;
  const int tb = blockIdx.x * 128 + tw * 64;
  const size_t base = (size_t)bh * T_ * HD_;
  const unsigned short* Qs[3] = {Q1 + base, Q2 + base, Q3 + base};
  const unsigned short* Kb = Kh + base;

  float lsum[3] = {0.f, 0.f, 0.f};
  for (int s0 = 0; s0 < T_; s0 += 128) {
    const int sb = s0 + sw * 64;
#pragma unroll
    for (int i = 0; i < 3; i++) {
      f32x4 acc[4][4];
#pragma unroll
      for (int mt = 0; mt < 4; mt++)
#pragma unroll
        for (int nt = 0; nt < 4; nt++) acc[mt][nt] = (f32x4)0.f;
#pragma unroll
      for (int kk = 0; kk < 2; kk++) {
        bfrag af[4], bf_[4];
#pragma unroll
        for (int mt = 0; mt < 4; mt++)
          af[mt] = *(const bfrag*)(Qs[i] + (size_t)(tb + mt * 16 + lrow) * HD_ + kk * 32 + quad * 8);
#pragma unroll
        for (int nt = 0; nt < 4; nt++)
          bf_[nt] = *(const bfrag*)(Kb + (size_t)(sb + nt * 16 + lrow) * HD_ + kk * 32 + quad * 8);
#pragma unroll
        for (int mt = 0; mt < 4; mt++)
#pragma unroll
          for (int nt = 0; nt < 4; nt++)
            acc[mt][nt] = __builtin_amdgcn_mfma_f32_16x16x32_bf16(af[mt], bf_[nt], acc[mt][nt], 0, 0, 0);
      }
      float s = 0.f;
#pragma unroll
      for (int mt = 0; mt < 4; mt++)
#pragma unroll
        for (int nt = 0; nt < 4; nt++)
#pragma unroll
          for (int ii = 0; ii < 4; ii++)
            s += __expf(acc[mt][nt][ii] * 0.25f);
      lsum[i] += s;
    }
  }
#pragma unroll
  for (int i = 0; i < 3; i++) {
    float v = lsum[i];
    for (int off = 32; off > 0; off >>= 1) v += __shfl_down(v, off, 64);
    if (lane == 0) atomicAdd(&sums[i * BH_ + bh], v);
  }
}

// ---------------------------------------------------------------- main attention
// Recompute exp; write a1; P = sum_i r_i*e_i -> LDS (C-layout -> A-layout); PV MFMA.
__global__ __launch_bounds__(256) void attn_main_kernel(
    const unsigned short* __restrict__ Q1, const unsigned short* __restrict__ Q2,
    const unsigned short* __restrict__ Q3, const unsigned short* __restrict__ Kh,
    const unsigned short* __restrict__ Vt, const float* __restrict__ sums,
    float* __restrict__ a1out, unsigned short* __restrict__ attn_out) {
  __shared__ unsigned short P[128 * 136];   // stride 136: 16B-aligned rows for ds_read_b128
  const int tid = threadIdx.x, lane = tid & 63, w = tid >> 6;
  const int lrow = lane & 15, quad = lane >> 4;
  const int tw = w >> 1, sw = w & 1, dw = sw;
  const int bh = blockIdx.y;
  const int b = bh >> 4, h = bh & 15;
  const int tb = blockIdx.x * 128 + tw * 64;
  const size_t base = (size_t)bh * T_ * HD_;
  const unsigned short* Qs[3] = {Q1 + base, Q2 + base, Q3 + base};
  const unsigned short* Kb = Kh + base;
  const unsigned short* Vb = Vt + (size_t)bh * HD_ * T_;

  float r[3];
#pragma unroll
  for (int i = 0; i < 3; i++) r[i] = (float)T_ / (3.f * sums[i * BH_ + bh]);
  const float a1s = 3.f * r[0];

  f32x4 oacc[4][2];
#pragma unroll
  for (int mt = 0; mt < 4; mt++) { oacc[mt][0] = (f32x4)0.f; oacc[mt][1] = (f32x4)0.f; }

  for (int s0 = 0; s0 < T_; s0 += 128) {
    const int sb = s0 + sw * 64;
    f32x4 pc[4][4];
#pragma unroll
    for (int mt = 0; mt < 4; mt++)
#pragma unroll
      for (int nt = 0; nt < 4; nt++) pc[mt][nt] = (f32x4)0.f;

#pragma unroll
    for (int i = 0; i < 3; i++) {
      f32x4 acc[4][4];
#pragma unroll
      for (int mt = 0; mt < 4; mt++)
#pragma unroll
        for (int nt = 0; nt < 4; nt++) acc[mt][nt] = (f32x4)0.f;
#pragma unroll
      for (int kk = 0; kk < 2; kk++) {
        bfrag af[4], bf_[4];
#pragma unroll
        for (int mt = 0; mt < 4; mt++)
          af[mt] = *(const bfrag*)(Qs[i] + (size_t)(tb + mt * 16 + lrow) * HD_ + kk * 32 + quad * 8);
#pragma unroll
        for (int nt = 0; nt < 4; nt++)
          bf_[nt] = *(const bfrag*)(Kb + (size_t)(sb + nt * 16 + lrow) * HD_ + kk * 32 + quad * 8);
#pragma unroll
        for (int mt = 0; mt < 4; mt++)
#pragma unroll
          for (int nt = 0; nt < 4; nt++)
            acc[mt][nt] = __builtin_amdgcn_mfma_f32_16x16x32_bf16(af[mt], bf_[nt], acc[mt][nt], 0, 0, 0);
      }
      const float ri = r[i];
#pragma unroll
      for (int mt = 0; mt < 4; mt++)
#pragma unroll
        for (int nt = 0; nt < 4; nt++)
#pragma unroll
          for (int ii = 0; ii < 4; ii++) {
            const float e = __expf(acc[mt][nt][ii] * 0.25f);
            pc[mt][nt][ii] += ri * e;
            if (i == 0) {
              const int t = tb + mt * 16 + quad * 4 + ii;
              const int s = sb + nt * 16 + lrow;
              a1out[((size_t)bh * T_ + t) * T_ + s] = e * a1s;
            }
          }
    }
    __syncthreads();   // prev-iter P reads complete
#pragma unroll
    for (int mt = 0; mt < 4; mt++)
#pragma unroll
      for (int nt = 0; nt < 4; nt++)
#pragma unroll
        for (int ii = 0; ii < 4; ii++) {
          const int tl = tw * 64 + mt * 16 + quad * 4 + ii;
          const int sl = sw * 64 + nt * 16 + lrow;
          P[tl * 136 + sl] = f2b(pc[mt][nt][ii]);
        }
    __syncthreads();   // P ready
    // PV: wave covers t[tw*64 .. +63] x d[dw*32 .. +31]
#pragma unroll
    for (int kk = 0; kk < 4; kk++) {
      bfrag pf[4], vf[2];
#pragma unroll
      for (int mt = 0; mt < 4; mt++)
        pf[mt] = *(const bfrag*)(P + (tw * 64 + mt * 16 + lrow) * 136 + kk * 32 + quad * 8);
#pragma unroll
      for (int nt = 0; nt < 2; nt++)
        vf[nt] = *(const bfrag*)(Vb + (size_t)(dw * 32 + nt * 16 + lrow) * T_ + s0 + kk * 32 + quad * 8);
#pragma unroll
      for (int mt = 0; mt < 4; mt++)
#pragma unroll
        for (int nt = 0; nt < 2; nt++)
          oacc[mt][nt] = __builtin_amdgcn_mfma_f32_16x16x32_bf16(pf[mt], vf[nt], oacc[mt][nt], 0, 0, 0);
    }
  }
  // attn_out[b][t][h*64+d] bf16
#pragma unroll
  for (int mt = 0; mt < 4; mt++)
#pragma unroll
    for (int nt = 0; nt < 2; nt++)
#pragma unroll
      for (int ii = 0; ii < 4; ii++) {
        const int t = tb + mt * 16 + quad * 4 + ii;
        const int dd = dw * 32 + nt * 16 + lrow;
        attn_out[((size_t)(b * T_ + t)) * E_ + h * HD_ + dd] = f2b(oacc[mt][nt][ii]);
      }
}

// ---------------------------------------------------------------- output projection
__global__ __launch_bounds__(256) void outproj_kernel(
    const unsigned short* __restrict__ Ab, const unsigned short* __restrict__ Wb,
    const float* __restrict__ bias, float* __restrict__ out) {
  __shared__ unsigned short As[128 * 32];
  __shared__ unsigned short Bs[128 * 32];
  const int m0 = blockIdx.y * 128, n0 = blockIdx.x * 128;
  f32x4 acc[4][4];
#pragma unroll
  for (int mt = 0; mt < 4; mt++)
#pragma unroll
    for (int nt = 0; nt < 4; nt++) acc[mt][nt] = (f32x4)0.f;

  mm128_core(Ab, Wb, m0, n0, As, Bs, acc);

  const int tid = threadIdx.x, lane = tid & 63, w = tid >> 6;
  const int lrow = lane & 15, quad = lane >> 4;
  const int wm = (w >> 1) * 64, wn = (w & 1) * 64;
  float bv[4];
#pragma unroll
  for (int nt = 0; nt < 4; nt++) bv[nt] = bias[n0 + wn + nt * 16 + lrow];
#pragma unroll
  for (int mt = 0; mt < 4; mt++)
#pragma unroll
    for (int nt = 0; nt < 4; nt++)
#pragma unroll
      for (int ii = 0; ii < 4; ii++) {
        const int m = m0 + wm + mt * 16 + quad * 4 + ii;
        const int n = n0 + wn + nt * 16 + lrow;
        out[(size_t)m * E_ + n] = acc[mt][nt][ii] + bv[nt];
      }
}

// ---------------------------------------------------------------- launcher
extern "C" void kernel_launch(void* const* d_in, const int* in_sizes, int n_in,
                              void* d_out, int out_size, void* d_ws, size_t ws_size,
                              hipStream_t stream) {
  const float* q1f  = (const float*)d_in[0];
  const float* q2f  = (const float*)d_in[1];
  const float* keyf = (const float*)d_in[2];
  const float* valf = (const float*)d_in[3];
  const float* Wq  = (const float*)d_in[4];  const float* bq  = (const float*)d_in[5];
  const float* Wq2 = (const float*)d_in[6];  const float* bq2 = (const float*)d_in[7];
  const float* Wq3 = (const float*)d_in[8];  const float* bq3 = (const float*)d_in[9];
  const float* Wk  = (const float*)d_in[10]; const float* bk  = (const float*)d_in[11];
  const float* Wv  = (const float*)d_in[12]; const float* bv  = (const float*)d_in[13];
  const float* Wo  = (const float*)d_in[14]; const float* bo  = (const float*)d_in[15];

  char* ws = (char*)d_ws;
  const size_t MB = 1024 * 1024;
  unsigned short* xq1  = (unsigned short*)(ws + 0 * MB);
  unsigned short* xq2  = (unsigned short*)(ws + 4 * MB);
  unsigned short* xkey = (unsigned short*)(ws + 8 * MB);
  unsigned short* xval = (unsigned short*)(ws + 12 * MB);
  unsigned short* wq   = (unsigned short*)(ws + 16 * MB);
  unsigned short* wq2  = (unsigned short*)(ws + 18 * MB);
  unsigned short* wq3  = (unsigned short*)(ws + 20 * MB);
  unsigned short* wk   = (unsigned short*)(ws + 22 * MB);
  unsigned short* wv   = (unsigned short*)(ws + 24 * MB);
  unsigned short* wo   = (unsigned short*)(ws + 26 * MB);
  unsigned short* Qh1  = (unsigned short*)(ws + 28 * MB);
  unsigned short* Qh2  = (unsigned short*)(ws + 32 * MB);
  unsigned short* Qh3  = (unsigned short*)(ws + 36 * MB);
  unsigned short* Kh   = (unsigned short*)(ws + 40 * MB);
  unsigned short* Vt   = (unsigned short*)(ws + 44 * MB);
  unsigned short* attn = (unsigned short*)(ws + 48 * MB);
  float* sums          = (float*)(ws + 52 * MB);

  // 1) fp32 -> bf16
  CvtArgs ca;
  const float* srcs[10] = {q1f, q2f, keyf, valf, Wq, Wq2, Wq3, Wk, Wv, Wo};
  unsigned short* dsts[10] = {xq1, xq2, xkey, xval, wq, wq2, wq3, wk, wv, wo};
  for (int i = 0; i < 10; i++) { ca.src[i] = srcs[i]; ca.dst[i] = dsts[i]; ca.n[i] = (i < 4) ? 2097152 : 1048576; }
  cvt_kernel<<<dim3(2048, 10), 256, 0, stream>>>(ca);

  hipMemsetAsync(sums, 0, 3 * BH_ * sizeof(float), stream);

  // 2) projections -> head layouts (V transposed)
  ProjArgs pa;
  const unsigned short* Xs[5] = {xq1, xq2, xkey, xkey, xval};
  const unsigned short* Ws_[5] = {wq, wq2, wq3, wk, wv};
  const float* Bi[5] = {bq, bq2, bq3, bk, bv};
  unsigned short* Ds[5] = {Qh1, Qh2, Qh3, Kh, Vt};
  for (int i = 0; i < 5; i++) { pa.X[i] = Xs[i]; pa.W[i] = Ws_[i]; pa.bias[i] = Bi[i]; pa.dst[i] = Ds[i]; }
  proj_kernel<<<dim3(8, 16, 5), 256, 0, stream>>>(pa);

  // 3) global softmax denominators
  attn_sums_kernel<<<dim3(8, BH_), 256, 0, stream>>>(Qh1, Qh2, Qh3, Kh, sums);

  // 4) attention: a1 + attn_out
  float* out = (float*)d_out;
  attn_main_kernel<<<dim3(8, BH_), 256, 0, stream>>>(Qh1, Qh2, Qh3, Kh, Vt, sums,
                                                     out + 2097152, attn);

  // 5) output projection
  outproj_kernel<<<dim3(8, 16), 256, 0, stream>>>(attn, wo, bo, out);
}